// Round 1
// baseline (223.078 us; speedup 1.0000x reference)
//
#include <hip/hip_runtime.h>

// Partial Radon transform:
//  x: (4, 1, 256, 256) f32 -> out: (4, 5, 256, 180) f32
//  out[n,s,w,a] = sum_h wts[s,h] * bilinear(img[n], iy[a,h,w], ix[a,h,w])
//  wts: 5 nested centered bands (2, 64, 128, 192, 256 rows), weight 1/count.

constexpr int WIDTH = 256;
constexpr int NANG  = 180;
constexpr int NBATCH = 4;
constexpr int NS    = 5;

__global__ __launch_bounds__(256) void radon_kernel(const float* __restrict__ x,
                                                    float* __restrict__ out) {
    const int blk = blockIdx.x;          // n * NANG + a
    const int n = blk / NANG;
    const int a = blk - n * NANG;
    const int w = threadIdx.x;

    const float theta = (float)a * (3.14159265358979323846f / 180.0f);
    float s, c;
    sincosf(theta, &s, &c);

    const float* __restrict__ img = x + (size_t)n * WIDTH * WIDTH;

    // Normalized coords: b(i) = (i+0.5)*(2/W) - 1
    const float bw  = ((float)w + 0.5f) * (2.0f / WIDTH) - 1.0f;
    const float bh0 = 0.5f * (2.0f / WIDTH) - 1.0f;

    // gx = c*bw + s*bh ; gy = -s*bw + c*bh
    // ix = ((gx+1)*W - 1)/2 ; iy = ((gy+1)*W - 1)/2
    // d(ix)/dh = s ; d(iy)/dh = c  (exactly)
    const float gx0 = c * bw + s * bh0;
    const float gy0 = -s * bw + c * bh0;
    const float ix0 = ((gx0 + 1.0f) * (float)WIDTH - 1.0f) * 0.5f;
    const float iy0 = ((gy0 + 1.0f) * (float)WIDTH - 1.0f) * 0.5f;

    float r0 = 0.f, r1 = 0.f, r2 = 0.f, r3 = 0.f, r4 = 0.f;

    auto sample = [&](int h) -> float {
        const float ix = fmaf((float)h, s, ix0);
        const float iy = fmaf((float)h, c, iy0);
        const float fx0 = floorf(ix), fy0 = floorf(iy);
        const float wx1 = ix - fx0, wy1 = iy - fy0;
        const float wx0 = 1.0f - wx1, wy0 = 1.0f - wy1;
        const int x0 = (int)fx0, y0 = (int)fy0;
        const int x1 = x0 + 1, y1 = y0 + 1;
        const bool vx0 = (unsigned)x0 < (unsigned)WIDTH;
        const bool vx1 = (unsigned)x1 < (unsigned)WIDTH;
        const bool vy0 = (unsigned)y0 < (unsigned)WIDTH;
        const bool vy1 = (unsigned)y1 < (unsigned)WIDTH;
        const int cx0 = min(max(x0, 0), WIDTH - 1);
        const int cx1 = min(max(x1, 0), WIDTH - 1);
        const int cy0 = min(max(y0, 0), WIDTH - 1);
        const int cy1 = min(max(y1, 0), WIDTH - 1);
        float acc;
        acc  = img[cy0 * WIDTH + cx0] * ((vy0 && vx0) ? wy0 * wx0 : 0.0f);
        acc += img[cy0 * WIDTH + cx1] * ((vy0 && vx1) ? wy0 * wx1 : 0.0f);
        acc += img[cy1 * WIDTH + cx0] * ((vy1 && vx0) ? wy1 * wx0 : 0.0f);
        acc += img[cy1 * WIDTH + cx1] * ((vy1 && vx1) ? wy1 * wx1 : 0.0f);
        return acc;
    };

    // Nested bands over h (band membership depends only on h):
    //  ring4: [0,32) u [224,256)   (outermost shell)
    //  ring3: [32,64) u [192,224)
    //  ring2: [64,96) u [160,192)
    //  ring1: [96,127) u [129,160)
    //  ring0: [127,129)            (innermost: |h-127.5| < 1)
    #pragma unroll 8
    for (int h = 0; h < 32; ++h)    r4 += sample(h);
    #pragma unroll 8
    for (int h = 32; h < 64; ++h)   r3 += sample(h);
    #pragma unroll 8
    for (int h = 64; h < 96; ++h)   r2 += sample(h);
    #pragma unroll 8
    for (int h = 96; h < 127; ++h)  r1 += sample(h);
    r0 += sample(127);
    r0 += sample(128);
    #pragma unroll 8
    for (int h = 129; h < 160; ++h) r1 += sample(h);
    #pragma unroll 8
    for (int h = 160; h < 192; ++h) r2 += sample(h);
    #pragma unroll 8
    for (int h = 192; h < 224; ++h) r3 += sample(h);
    #pragma unroll 8
    for (int h = 224; h < 256; ++h) r4 += sample(h);

    // out[n,s,w,a]; cumulative ring sums, scaled by 1/count
    float* o = out + (((size_t)n * NS) * WIDTH + (size_t)w) * NANG + (size_t)a;
    float cum = r0;
    o[0]                          = cum * (1.0f / 2.0f);
    cum += r1;
    o[(size_t)1 * WIDTH * NANG]   = cum * (1.0f / 64.0f);
    cum += r2;
    o[(size_t)2 * WIDTH * NANG]   = cum * (1.0f / 128.0f);
    cum += r3;
    o[(size_t)3 * WIDTH * NANG]   = cum * (1.0f / 192.0f);
    cum += r4;
    o[(size_t)4 * WIDTH * NANG]   = cum * (1.0f / 256.0f);
}

extern "C" void kernel_launch(void* const* d_in, const int* in_sizes, int n_in,
                              void* d_out, int out_size, void* d_ws, size_t ws_size,
                              hipStream_t stream) {
    const float* x = (const float*)d_in[0];
    float* out = (float*)d_out;
    radon_kernel<<<NBATCH * NANG, WIDTH, 0, stream>>>(x, out);
}

// Round 3
// 115.568 us; speedup vs baseline: 1.9303x; 1.9303x over previous
//
#include <hip/hip_runtime.h>

// Partial Radon transform:
//  x: (4, 1, 256, 256) f32 -> out: (4, 5, 256, 180) f32
//  out[n,s,w,a] = sum_h wts[s,h] * bilinear(img[n], iy[a,h,w], ix[a,h,w])
//  wts: 5 nested centered bands (2, 64, 128, 192, 256 rows), weight 1/count.
//
// Round 3: whole image staged in STATIC LDS as f16 (256 x 258 stride = 132 KB
// < 160 KB gfx950 limit; no dynamic-LDS attribute, no host API in launch).
// Row stride 258 => bank = (129*y + x/2) % 32, odd y-coefficient => <=3-way
// conflicts at every angle. Gathers become ds_read_u16.

constexpr int WIDTH  = 256;
constexpr int NANG   = 180;
constexpr int NBATCH = 4;
constexpr int NS     = 5;
constexpr int LSTR   = 258;   // f16 elements per LDS row (even => dword-aligned rows)

__device__ inline unsigned pack2_f16(float a, float b) {
    _Float16 ha = (_Float16)a, hb = (_Float16)b;
    unsigned short ua = __builtin_bit_cast(unsigned short, ha);
    unsigned short ub = __builtin_bit_cast(unsigned short, hb);
    return (unsigned)ua | ((unsigned)ub << 16);
}

__global__ __launch_bounds__(256) void radon_kernel(const float* __restrict__ x,
                                                    float* __restrict__ out) {
    __shared__ _Float16 lds[WIDTH * LSTR];   // 132096 B static

    const int blk = blockIdx.x;          // n * NANG + a
    const int n = blk / NANG;
    const int a = blk - n * NANG;
    const int t = threadIdx.x;
    const int w = t;

    const float* __restrict__ img = x + (size_t)n * WIDTH * WIDTH;

    // ---- Stage image -> LDS f16 (row stride LSTR) ----
    // 16384 float4 chunks; thread t takes chunks {k*256 + t}: y = 4k + t/64·0…
    for (int k = 0; k < 64; ++k) {
        const int chunk = k * 256 + t;
        const float4 v = ((const float4*)img)[chunk];
        const int px = chunk << 2;              // first pixel of the chunk
        const int y  = px >> 8;
        const int xx = px & 255;                // multiple of 4
        unsigned* dst = (unsigned*)&lds[y * LSTR + xx];   // byte off 4-aligned
        dst[0] = pack2_f16(v.x, v.y);
        dst[1] = pack2_f16(v.z, v.w);
    }
    __syncthreads();

    // ---- Per-(a,w) line walk ----
    const float theta = (float)a * (3.14159265358979323846f / 180.0f);
    float s, c;
    sincosf(theta, &s, &c);

    const float bw  = ((float)w + 0.5f) * (2.0f / WIDTH) - 1.0f;
    const float bh0 = 0.5f * (2.0f / WIDTH) - 1.0f;
    const float gx0 = c * bw + s * bh0;
    const float gy0 = -s * bw + c * bh0;
    const float ix0 = ((gx0 + 1.0f) * (float)WIDTH - 1.0f) * 0.5f;
    const float iy0 = ((gy0 + 1.0f) * (float)WIDTH - 1.0f) * 0.5f;

    float r0 = 0.f, r1 = 0.f, r2 = 0.f, r3 = 0.f, r4 = 0.f;

    auto sample = [&](int h) -> float {
        const float ix = fmaf((float)h, s, ix0);
        const float iy = fmaf((float)h, c, iy0);
        const float fx0 = floorf(ix), fy0 = floorf(iy);
        const float wx1 = ix - fx0, wy1 = iy - fy0;
        const float wx0 = 1.0f - wx1, wy0 = 1.0f - wy1;
        const int x0 = (int)fx0, y0 = (int)fy0;
        const int x1 = x0 + 1, y1 = y0 + 1;
        // fold validity into the weights
        const float wxa = ((unsigned)x0 < (unsigned)WIDTH) ? wx0 : 0.0f;
        const float wxb = ((unsigned)x1 < (unsigned)WIDTH) ? wx1 : 0.0f;
        const float wya = ((unsigned)y0 < (unsigned)WIDTH) ? wy0 : 0.0f;
        const float wyb = ((unsigned)y1 < (unsigned)WIDTH) ? wy1 : 0.0f;
        const int cx0 = min(max(x0, 0), WIDTH - 1);
        const int cx1 = min(max(x1, 0), WIDTH - 1);
        const int cy0 = min(max(y0, 0), WIDTH - 1);
        const int cy1 = min(max(y1, 0), WIDTH - 1);
        const int ra = cy0 * LSTR;
        const int rb = cy1 * LSTR;
        const float v00 = (float)lds[ra + cx0];
        const float v01 = (float)lds[ra + cx1];
        const float v10 = (float)lds[rb + cx0];
        const float v11 = (float)lds[rb + cx1];
        return wya * (wxa * v00 + wxb * v01) + wyb * (wxa * v10 + wxb * v11);
    };

    // Nested bands over h:
    //  ring4: [0,32) u [224,256); ring3: [32,64) u [192,224);
    //  ring2: [64,96) u [160,192); ring1: [96,127) u [129,160); ring0: {127,128}
    #pragma unroll 8
    for (int h = 0; h < 32; ++h)    r4 += sample(h);
    #pragma unroll 8
    for (int h = 32; h < 64; ++h)   r3 += sample(h);
    #pragma unroll 8
    for (int h = 64; h < 96; ++h)   r2 += sample(h);
    #pragma unroll 8
    for (int h = 96; h < 127; ++h)  r1 += sample(h);
    r0 += sample(127);
    r0 += sample(128);
    #pragma unroll 8
    for (int h = 129; h < 160; ++h) r1 += sample(h);
    #pragma unroll 8
    for (int h = 160; h < 192; ++h) r2 += sample(h);
    #pragma unroll 8
    for (int h = 192; h < 224; ++h) r3 += sample(h);
    #pragma unroll 8
    for (int h = 224; h < 256; ++h) r4 += sample(h);

    // out[n,s,w,a]; cumulative ring sums, scaled by 1/count
    float* o = out + (((size_t)n * NS) * WIDTH + (size_t)w) * NANG + (size_t)a;
    float cum = r0;
    o[0]                          = cum * (1.0f / 2.0f);
    cum += r1;
    o[(size_t)1 * WIDTH * NANG]   = cum * (1.0f / 64.0f);
    cum += r2;
    o[(size_t)2 * WIDTH * NANG]   = cum * (1.0f / 128.0f);
    cum += r3;
    o[(size_t)3 * WIDTH * NANG]   = cum * (1.0f / 192.0f);
    cum += r4;
    o[(size_t)4 * WIDTH * NANG]   = cum * (1.0f / 256.0f);
}

extern "C" void kernel_launch(void* const* d_in, const int* in_sizes, int n_in,
                              void* d_out, int out_size, void* d_ws, size_t ws_size,
                              hipStream_t stream) {
    const float* x = (const float*)d_in[0];
    float* out = (float*)d_out;
    radon_kernel<<<NBATCH * NANG, WIDTH, 0, stream>>>(x, out);
}

// Round 4
// 73.265 us; speedup vs baseline: 3.0448x; 1.5774x over previous
//
#include <hip/hip_runtime.h>

// Partial Radon transform:
//  x: (4, 1, 256, 256) f32 -> out: (4, 5, 256, 180) f32
//  out[n,s,w,a] = sum_h wts[s,h] * bilinear(img[n], iy[a,h,w], ix[a,h,w])
//  wts: 5 nested centered bands (2, 64, 128, 192, 256 rows), weight 1/count.
//
// Round 4: (a) 768-thread blocks (12 waves = 3/SIMD vs 4 waves before) —
// LDS-capacity pins us to 1 block/CU, so occupancy must come from block size.
// h-range split into thirds [0,96)/[96,160)/[160,256) aligned to ring
// boundaries; partial ring sums reduced through LDS (reused) at the end.
// (b) LDS row stride 258 -> 270 f16: dword stride 135 == 7 (mod 32), so
// bank = (7*y + x/2) % 32 spreads lanes at every angle (258 gave ~3-way
// conflicts at +-45 deg: 9.05M conflict cycles measured).

constexpr int WIDTH  = 256;
constexpr int NANG   = 180;
constexpr int NBATCH = 4;
constexpr int NS     = 5;
constexpr int LSTR   = 270;   // f16 elements per LDS row; 135 dwords, 135%32=7

__device__ inline unsigned pack2_f16(float a, float b) {
    _Float16 ha = (_Float16)a, hb = (_Float16)b;
    unsigned short ua = __builtin_bit_cast(unsigned short, ha);
    unsigned short ub = __builtin_bit_cast(unsigned short, hb);
    return (unsigned)ua | ((unsigned)ub << 16);
}

__global__ __launch_bounds__(768) void radon_kernel(const float* __restrict__ x,
                                                    float* __restrict__ out) {
    __shared__ _Float16 lds[WIDTH * LSTR];   // 138240 B static

    const int blk = blockIdx.x;          // n * NANG + a
    const int n = blk / NANG;
    const int a = blk - n * NANG;
    const int t = threadIdx.x;
    const int w = t & 255;
    const int third = t >> 8;            // 0,1,2 -> h range

    const float* __restrict__ img = x + (size_t)n * WIDTH * WIDTH;

    // ---- Stage image -> LDS f16 (row stride LSTR) ----
    // 16384 float4 chunks across 768 threads.
    for (int chunk = t; chunk < 16384; chunk += 768) {
        const float4 v = ((const float4*)img)[chunk];
        const int px = chunk << 2;
        const int y  = px >> 8;
        const int xx = px & 255;                // multiple of 4
        unsigned* dst = (unsigned*)&lds[y * LSTR + xx];   // 4-aligned (LSTR even)
        dst[0] = pack2_f16(v.x, v.y);
        dst[1] = pack2_f16(v.z, v.w);
    }
    __syncthreads();

    // ---- Per-(a,w) line walk over this third's h range ----
    const float theta = (float)a * (3.14159265358979323846f / 180.0f);
    float s, c;
    sincosf(theta, &s, &c);

    const float bw  = ((float)w + 0.5f) * (2.0f / WIDTH) - 1.0f;
    const float bh0 = 0.5f * (2.0f / WIDTH) - 1.0f;
    const float gx0 = c * bw + s * bh0;
    const float gy0 = -s * bw + c * bh0;
    const float ix0 = ((gx0 + 1.0f) * (float)WIDTH - 1.0f) * 0.5f;
    const float iy0 = ((gy0 + 1.0f) * (float)WIDTH - 1.0f) * 0.5f;

    float r0 = 0.f, r1 = 0.f, r2 = 0.f, r3 = 0.f, r4 = 0.f;

    auto sample = [&](int h) -> float {
        const float ix = fmaf((float)h, s, ix0);
        const float iy = fmaf((float)h, c, iy0);
        const float fx0 = floorf(ix), fy0 = floorf(iy);
        const float wx1 = ix - fx0, wy1 = iy - fy0;
        const float wx0 = 1.0f - wx1, wy0 = 1.0f - wy1;
        const int x0 = (int)fx0, y0 = (int)fy0;
        const int x1 = x0 + 1, y1 = y0 + 1;
        const float wxa = ((unsigned)x0 < (unsigned)WIDTH) ? wx0 : 0.0f;
        const float wxb = ((unsigned)x1 < (unsigned)WIDTH) ? wx1 : 0.0f;
        const float wya = ((unsigned)y0 < (unsigned)WIDTH) ? wy0 : 0.0f;
        const float wyb = ((unsigned)y1 < (unsigned)WIDTH) ? wy1 : 0.0f;
        const int cx0 = min(max(x0, 0), WIDTH - 1);
        const int cx1 = min(max(x1, 0), WIDTH - 1);
        const int cy0 = min(max(y0, 0), WIDTH - 1);
        const int cy1 = min(max(y1, 0), WIDTH - 1);
        const int ra = cy0 * LSTR;
        const int rb = cy1 * LSTR;
        const float v00 = (float)lds[ra + cx0];
        const float v01 = (float)lds[ra + cx1];
        const float v10 = (float)lds[rb + cx0];
        const float v11 = (float)lds[rb + cx1];
        return wya * (wxa * v00 + wxb * v01) + wyb * (wxa * v10 + wxb * v11);
    };

    // Ring bands: r4:[0,32)u[224,256)  r3:[32,64)u[192,224)
    //             r2:[64,96)u[160,192) r1:[96,127)u[129,160) r0:{127,128}
    if (third == 0) {
        #pragma unroll 8
        for (int h = 0; h < 32; ++h)    r4 += sample(h);
        #pragma unroll 8
        for (int h = 32; h < 64; ++h)   r3 += sample(h);
        #pragma unroll 8
        for (int h = 64; h < 96; ++h)   r2 += sample(h);
    } else if (third == 1) {
        #pragma unroll 8
        for (int h = 96; h < 127; ++h)  r1 += sample(h);
        r0 += sample(127);
        r0 += sample(128);
        #pragma unroll 8
        for (int h = 129; h < 160; ++h) r1 += sample(h);
    } else {
        #pragma unroll 8
        for (int h = 160; h < 192; ++h) r2 += sample(h);
        #pragma unroll 8
        for (int h = 192; h < 224; ++h) r3 += sample(h);
        #pragma unroll 8
        for (int h = 224; h < 256; ++h) r4 += sample(h);
    }

    // ---- Cross-third reduction via LDS reuse ----
    __syncthreads();                       // all sampling done; image dead
    float* red = (float*)lds;              // 3*256*5 floats = 15360 B
    const int base = t * NS;               // (third*256 + w) * 5
    red[base + 0] = r0;
    red[base + 1] = r1;
    red[base + 2] = r2;
    red[base + 3] = r3;
    red[base + 4] = r4;
    __syncthreads();

    if (t < 256) {
        const int b0 = t * NS, b1 = (256 + t) * NS, b2 = (512 + t) * NS;
        const float s0 = red[b0 + 0] + red[b1 + 0] + red[b2 + 0];
        const float s1 = red[b0 + 1] + red[b1 + 1] + red[b2 + 1];
        const float s2 = red[b0 + 2] + red[b1 + 2] + red[b2 + 2];
        const float s3 = red[b0 + 3] + red[b1 + 3] + red[b2 + 3];
        const float s4 = red[b0 + 4] + red[b1 + 4] + red[b2 + 4];

        float* o = out + (((size_t)n * NS) * WIDTH + (size_t)t) * NANG + (size_t)a;
        float cum = s0;
        o[0]                          = cum * (1.0f / 2.0f);
        cum += s1;
        o[(size_t)1 * WIDTH * NANG]   = cum * (1.0f / 64.0f);
        cum += s2;
        o[(size_t)2 * WIDTH * NANG]   = cum * (1.0f / 128.0f);
        cum += s3;
        o[(size_t)3 * WIDTH * NANG]   = cum * (1.0f / 192.0f);
        cum += s4;
        o[(size_t)4 * WIDTH * NANG]   = cum * (1.0f / 256.0f);
    }
}

extern "C" void kernel_launch(void* const* d_in, const int* in_sizes, int n_in,
                              void* d_out, int out_size, void* d_ws, size_t ws_size,
                              hipStream_t stream) {
    const float* x = (const float*)d_in[0];
    float* out = (float*)d_out;
    radon_kernel<<<NBATCH * NANG, 768, 0, stream>>>(x, out);
}

// Round 5
// 60.978 us; speedup vs baseline: 3.6583x; 1.2015x over previous
//
#include <hip/hip_runtime.h>

// Partial Radon transform:
//  x: (4, 1, 256, 256) f32 -> out: (4, 5, 256, 180) f32
//  out[n,s,w,a] = sum_h wts[s,h] * bilinear(img[n], iy[a,h,w], ix[a,h,w])
//
// Round 5:
//  (a) zero-padded LDS image (+2 each side) + v_med3_f32 clamp of the
//      continuous coords -> no per-corner validity masks/clamps (~45 -> ~24
//      VALU ops per sample); 4 corner reads = 1 addr + offset imms 0/2/540/542.
//  (b) angle-dependent layout: store transposed when |cos|>|sin| so the
//      per-lane bank step delta = 7*dslow + dfast/2 stays in [4.6, 7] at every
//      angle (linear layouts always resonate somewhere; picking the layout per
//      block keeps all angles off the bad resonances).
//  (c) 1024-thread blocks (16 waves = 4/SIMD), h split in quarters aligned to
//      ring boundaries; partial ring sums reduced via reused LDS.

constexpr int WIDTH  = 256;
constexpr int NANG   = 180;
constexpr int NBATCH = 4;
constexpr int NS     = 5;
constexpr int LSTR   = 270;   // u16 per slow-row: 540 B, 135 dwords, 135%32=7
constexpr int ROWS   = 260;   // padded slow extent: orig -2..257

__device__ inline unsigned pack2_f16(float a, float b) {
    _Float16 ha = (_Float16)a, hb = (_Float16)b;
    unsigned short ua = __builtin_bit_cast(unsigned short, ha);
    unsigned short ub = __builtin_bit_cast(unsigned short, hb);
    return (unsigned)ua | ((unsigned)ub << 16);
}

__global__ __launch_bounds__(1024) void radon_kernel(const float* __restrict__ x,
                                                     float* __restrict__ out) {
    __shared__ _Float16 lds[ROWS * LSTR];   // 140,400 B static

    const int blk = blockIdx.x;          // n * NANG + a
    const int n = blk / NANG;
    const int a = blk - n * NANG;
    const int t = threadIdx.x;
    const int w = t & 255;
    const int quarter = t >> 8;          // 0..3 -> h range [64q, 64q+64)

    const float* __restrict__ img = x + (size_t)n * WIDTH * WIDTH;

    const float theta = (float)a * 0.017453292519943295f;
    float s, c;
    sincosf(theta, &s, &c);
    const bool transp = (c * c > s * s);   // theta<45 or theta>135

    // ---- Zero-fill entire LDS (covers borders + unused pad) ----
    unsigned* l32 = (unsigned*)lds;
    for (int i = t; i < ROWS * LSTR / 2; i += 1024) l32[i] = 0u;
    __syncthreads();

    // ---- Stage image (interior at padded +2), layout chosen per block ----
    if (!transp) {
        // slow=y, fast=x. One dword (x-pair) per thread-iter; coalesced float2
        // reads; LDS banks advance 1/lane -> conflict-free.
        for (int d = t; d < 32768; d += 1024) {
            const int y = d >> 7, xd = d & 127;       // orig x pair (2xd, 2xd+1)
            const float2 v = ((const float2*)img)[d]; // img[y][2xd..2xd+1]
            *(unsigned*)&lds[(y + 2) * LSTR + 2 * xd + 2] = pack2_f16(v.x, v.y);
        }
    } else {
        // slow=x, fast=y. Lane<->x (coalesced global rows), pack y-pairs;
        // LDS addr step 540 B/lane -> bank step 7 -> conflict-free.
        for (int yp = quarter; yp < 128; yp += 4) {
            const int y = 2 * yp;
            const float v0 = img[y * WIDTH + w];
            const float v1 = img[y * WIDTH + WIDTH + w];
            *(unsigned*)&lds[(w + 2) * LSTR + y + 2] = pack2_f16(v0, v1);
        }
    }
    __syncthreads();

    // ---- Per-(a,w) line walk over this quarter's h range ----
    const float bw  = ((float)w + 0.5f) * (2.0f / WIDTH) - 1.0f;
    const float bh0 = 0.5f * (2.0f / WIDTH) - 1.0f;
    const float gx0 = c * bw + s * bh0;
    const float gy0 = -s * bw + c * bh0;
    const float ix0 = ((gx0 + 1.0f) * (float)WIDTH - 1.0f) * 0.5f;
    const float iy0 = ((gy0 + 1.0f) * (float)WIDTH - 1.0f) * 0.5f;

    // unified (fast, slow) coords, +2 padding folded into the base
    const float fast0 = (transp ? iy0 : ix0) + 2.0f;
    const float slow0 = (transp ? ix0 : iy0) + 2.0f;
    const float dfast = transp ? c : s;     // d/dh
    const float dslow = transp ? s : c;

    float r0 = 0.f, r1 = 0.f, r2 = 0.f, r3 = 0.f, r4 = 0.f;

    auto sample = [&](int h, float& r) {
        float fa = fmaf((float)h, dfast, fast0);
        float sl = fmaf((float)h, dslow, slow0);
        fa = __builtin_amdgcn_fmed3f(fa, 1.0f, 258.0f);   // clamp to padded [-1,256]
        sl = __builtin_amdgcn_fmed3f(sl, 1.0f, 258.0f);
        const float ff = floorf(fa), fs = floorf(sl);
        const float wf1 = fa - ff, wf0 = 1.0f - wf1;
        const float ws1 = sl - fs, ws0 = 1.0f - ws1;
        const int fi = (int)ff, si = (int)fs;
        const _Float16* p = &lds[si * LSTR + fi];
        const float v00 = (float)p[0];
        const float v01 = (float)p[1];
        const float v10 = (float)p[LSTR];
        const float v11 = (float)p[LSTR + 1];
        const float row0 = fmaf(wf1, v01, wf0 * v00);
        const float row1 = fmaf(wf1, v11, wf0 * v10);
        r = fmaf(ws0, row0, r);
        r = fmaf(ws1, row1, r);
    };

    // Ring bands: r4:[0,32)u[224,256)  r3:[32,64)u[192,224)
    //             r2:[64,96)u[160,192) r1:[96,127)u[129,160) r0:{127,128}
    if (quarter == 0) {
        #pragma unroll 8
        for (int h = 0; h < 32; ++h)    sample(h, r4);
        #pragma unroll 8
        for (int h = 32; h < 64; ++h)   sample(h, r3);
    } else if (quarter == 1) {
        #pragma unroll 8
        for (int h = 64; h < 96; ++h)   sample(h, r2);
        #pragma unroll 8
        for (int h = 96; h < 127; ++h)  sample(h, r1);
        sample(127, r0);
    } else if (quarter == 2) {
        sample(128, r0);
        #pragma unroll 8
        for (int h = 129; h < 160; ++h) sample(h, r1);
        #pragma unroll 8
        for (int h = 160; h < 192; ++h) sample(h, r2);
    } else {
        #pragma unroll 8
        for (int h = 192; h < 224; ++h) sample(h, r3);
        #pragma unroll 8
        for (int h = 224; h < 256; ++h) sample(h, r4);
    }

    // ---- Cross-quarter reduction via LDS reuse ----
    __syncthreads();                       // sampling done; image dead
    float* red = (float*)lds;              // 1024*5 floats = 20,480 B
    const int base = t * NS;
    red[base + 0] = r0;
    red[base + 1] = r1;
    red[base + 2] = r2;
    red[base + 3] = r3;
    red[base + 4] = r4;
    __syncthreads();

    if (t < 256) {
        const int b0 = t * NS, b1 = b0 + 256 * NS, b2 = b0 + 512 * NS, b3 = b0 + 768 * NS;
        const float s0 = (red[b0+0] + red[b1+0]) + (red[b2+0] + red[b3+0]);
        const float s1 = (red[b0+1] + red[b1+1]) + (red[b2+1] + red[b3+1]);
        const float s2 = (red[b0+2] + red[b1+2]) + (red[b2+2] + red[b3+2]);
        const float s3 = (red[b0+3] + red[b1+3]) + (red[b2+3] + red[b3+3]);
        const float s4 = (red[b0+4] + red[b1+4]) + (red[b2+4] + red[b3+4]);

        float* o = out + (((size_t)n * NS) * WIDTH + (size_t)t) * NANG + (size_t)a;
        float cum = s0;
        o[0]                          = cum * (1.0f / 2.0f);
        cum += s1;
        o[(size_t)1 * WIDTH * NANG]   = cum * (1.0f / 64.0f);
        cum += s2;
        o[(size_t)2 * WIDTH * NANG]   = cum * (1.0f / 128.0f);
        cum += s3;
        o[(size_t)3 * WIDTH * NANG]   = cum * (1.0f / 192.0f);
        cum += s4;
        o[(size_t)4 * WIDTH * NANG]   = cum * (1.0f / 256.0f);
    }
}

extern "C" void kernel_launch(void* const* d_in, const int* in_sizes, int n_in,
                              void* d_out, int out_size, void* d_ws, size_t ws_size,
                              hipStream_t stream) {
    const float* x = (const float*)d_in[0];
    float* out = (float*)d_out;
    radon_kernel<<<NBATCH * NANG, 1024, 0, stream>>>(x, out);
}